// Round 1
// baseline (2084.096 us; speedup 1.0000x reference)
//
#include <hip/hip_runtime.h>

// GSModel fused pipeline, fp32 baseline.
// B=128 graphs, S=256 nodes/graph, D=256 feat, L=3 GIN layers, E=524288 edges/side.
// Design notes:
//  - segment_sum via CSR build (edges layer-invariant) + wave-per-node gather (no float atomics)
//  - GEMM: 256 thr/block, tile M=128 x N=256(full) x KC=32, 8x16 acc/thread, LDS staged
//  - BN stats fused into 2nd GIN GEMM epilogue (colsum/colsumsq, block-reduced then atomic)
//  - scores + gumbel + 20 sinkhorn iters + colsum(P).rowsum(g2) fused: 1 block/graph,
//    log_alpha register-resident (64 f32/thread x 1024 thr)
//  - sum(g1 - P@g2) = sum(g1) - dot(colsum P, rowsum g2)  -> no P@g2 matmul

constexpr int NNODE = 32768;
constexpr int NEDGE = 524288;

// ---------------- CSR build ----------------
__global__ void k_degree(const int* __restrict__ dst, int* __restrict__ cnt) {
  int e = blockIdx.x * 256 + threadIdx.x;
  atomicAdd(&cnt[dst[e]], 1);
}

__global__ void k_scan(const int* __restrict__ cnt, int* __restrict__ off, int* __restrict__ cur) {
  __shared__ int sh[1024];
  int t = threadIdx.x;
  int base = t * 32;
  int loc[32];
  int s = 0;
#pragma unroll
  for (int j = 0; j < 32; j++) { loc[j] = cnt[base + j]; s += loc[j]; }
  sh[t] = s;
  __syncthreads();
  for (int d = 1; d < 1024; d <<= 1) {
    int v = (t >= d) ? sh[t - d] : 0;
    __syncthreads();
    sh[t] += v;
    __syncthreads();
  }
  int run = sh[t] - s;
#pragma unroll
  for (int j = 0; j < 32; j++) { off[base + j] = run; cur[base + j] = run; run += loc[j]; }
  if (t == 1023) off[NNODE] = run;
}

__global__ void k_scatter(const int* __restrict__ src, const int* __restrict__ dst,
                          int* __restrict__ cur, int* __restrict__ srcs) {
  int e = blockIdx.x * 256 + threadIdx.x;
  int d = dst[e];
  int p = atomicAdd(&cur[d], 1);
  srcs[p] = src[e];
}

// ---------------- aggregate: out = (1+eps)*x + segment_sum, eps=1 ----------------
__global__ void k_aggregate(const float* __restrict__ x, const int* __restrict__ off,
                            const int* __restrict__ srcs, float* __restrict__ out) {
  int w = (blockIdx.x * blockDim.x + threadIdx.x) >> 6;   // node id (wave per node)
  int lane = threadIdx.x & 63;
  const float4* xv = (const float4*)x;
  float4 a = xv[(size_t)w * 64 + lane];
  float ax = 2.f * a.x, ay = 2.f * a.y, az = 2.f * a.z, aw = 2.f * a.w;
  int e0 = off[w], e1 = off[w + 1];
  for (int e = e0; e < e1; e++) {
    int sI = srcs[e];
    float4 v = xv[(size_t)sI * 64 + lane];
    ax += v.x; ay += v.y; az += v.z; aw += v.w;
  }
  float4 r; r.x = ax; r.y = ay; r.z = az; r.w = aw;
  ((float4*)out)[(size_t)w * 64 + lane] = r;
}

// ---------------- GEMM: C[32768x256] = A[32768x256] @ Wm[256x256] (+bias) ----------------
// EPI: 0 = plain, 1 = relu, 2 = plain + column sum/sumsq stats (for BatchNorm)
template <int EPI, bool HASB>
__global__ __launch_bounds__(256) void k_gemm(
    const float* __restrict__ A, const float* __restrict__ Wm,
    const float* __restrict__ bias, float* __restrict__ C,
    float* __restrict__ colsum, float* __restrict__ colsq) {
  __shared__ float As[128][36];   // rows x K-chunk, pad 36 to dodge bank conflicts
  __shared__ float Ws[32][256];   // K-chunk x N
  int tid = threadIdx.x;
  int tx = tid & 15, ty = tid >> 4;
  int m0 = blockIdx.x * 128;

  float acc[8][16];
#pragma unroll
  for (int r = 0; r < 8; r++)
#pragma unroll
    for (int c = 0; c < 16; c++) acc[r][c] = 0.f;

  for (int k0 = 0; k0 < 256; k0 += 32) {
#pragma unroll
    for (int it = 0; it < 4; it++) {
      int fid = tid + it * 256;
      int row = fid >> 3, cg = (fid & 7) * 4;
      float4 v = *(const float4*)&A[(size_t)(m0 + row) * 256 + k0 + cg];
      *(float4*)&As[row][cg] = v;
    }
#pragma unroll
    for (int it = 0; it < 8; it++) {
      int fid = tid + it * 256;
      int kr = fid >> 6, cg = (fid & 63) * 4;
      float4 v = *(const float4*)&Wm[(size_t)(k0 + kr) * 256 + cg];
      *(float4*)&Ws[kr][cg] = v;
    }
    __syncthreads();
#pragma unroll
    for (int kk = 0; kk < 32; kk += 4) {
      float afv[8][4];
#pragma unroll
      for (int r = 0; r < 8; r++) {
        float4 t4 = *(const float4*)&As[ty + 16 * r][kk];
        afv[r][0] = t4.x; afv[r][1] = t4.y; afv[r][2] = t4.z; afv[r][3] = t4.w;
      }
#pragma unroll
      for (int dk = 0; dk < 4; dk++) {
        float wf[4][4];
#pragma unroll
        for (int jj = 0; jj < 4; jj++) {
          float4 t4 = *(const float4*)&Ws[kk + dk][tx * 4 + 64 * jj];
          wf[jj][0] = t4.x; wf[jj][1] = t4.y; wf[jj][2] = t4.z; wf[jj][3] = t4.w;
        }
#pragma unroll
        for (int r = 0; r < 8; r++) {
          float a = afv[r][dk];
#pragma unroll
          for (int jj = 0; jj < 4; jj++) {
#pragma unroll
            for (int c = 0; c < 4; c++)
              acc[r][jj * 4 + c] = fmaf(a, wf[jj][c], acc[r][jj * 4 + c]);
          }
        }
      }
    }
    __syncthreads();
  }

  float bf[16];
#pragma unroll
  for (int jj = 0; jj < 4; jj++) {
    if (HASB) {
      float4 b4 = *(const float4*)&bias[tx * 4 + 64 * jj];
      bf[jj * 4 + 0] = b4.x; bf[jj * 4 + 1] = b4.y; bf[jj * 4 + 2] = b4.z; bf[jj * 4 + 3] = b4.w;
    } else {
      bf[jj * 4 + 0] = bf[jj * 4 + 1] = bf[jj * 4 + 2] = bf[jj * 4 + 3] = 0.f;
    }
  }

  float ps[16], pq[16];
  if constexpr (EPI == 2) {
#pragma unroll
    for (int c = 0; c < 16; c++) { ps[c] = 0.f; pq[c] = 0.f; }
  }

#pragma unroll
  for (int r = 0; r < 8; r++) {
    int row = m0 + ty + 16 * r;
#pragma unroll
    for (int jj = 0; jj < 4; jj++) {
      float v[4];
#pragma unroll
      for (int c = 0; c < 4; c++) {
        float o = acc[r][jj * 4 + c] + bf[jj * 4 + c];
        if constexpr (EPI == 1) o = fmaxf(o, 0.f);
        if constexpr (EPI == 2) { ps[jj * 4 + c] += o; pq[jj * 4 + c] += o * o; }
        v[c] = o;
      }
      float4 o4; o4.x = v[0]; o4.y = v[1]; o4.z = v[2]; o4.w = v[3];
      *(float4*)&C[(size_t)row * 256 + tx * 4 + 64 * jj] = o4;
    }
  }

  if constexpr (EPI == 2) {
    float* red = &Ws[0][0];   // reuse as [16][256]
#pragma unroll
    for (int jj = 0; jj < 4; jj++) {
      float4 w4; w4.x = ps[jj * 4 + 0]; w4.y = ps[jj * 4 + 1]; w4.z = ps[jj * 4 + 2]; w4.w = ps[jj * 4 + 3];
      *(float4*)&red[ty * 256 + tx * 4 + 64 * jj] = w4;
    }
    __syncthreads();
    if (tid < 256) {
      float s = 0.f;
#pragma unroll
      for (int q = 0; q < 16; q++) s += red[q * 256 + tid];
      atomicAdd(&colsum[tid], s);
    }
    __syncthreads();
#pragma unroll
    for (int jj = 0; jj < 4; jj++) {
      float4 w4; w4.x = pq[jj * 4 + 0]; w4.y = pq[jj * 4 + 1]; w4.z = pq[jj * 4 + 2]; w4.w = pq[jj * 4 + 3];
      *(float4*)&red[ty * 256 + tx * 4 + 64 * jj] = w4;
    }
    __syncthreads();
    if (tid < 256) {
      float s = 0.f;
#pragma unroll
      for (int q = 0; q < 16; q++) s += red[q * 256 + tid];
      atomicAdd(&colsq[tid], s);
    }
  }
}

// ---------------- BatchNorm apply + relu ----------------
__global__ void k_bnapply(const float* __restrict__ h, const float* __restrict__ cs,
                          const float* __restrict__ cq, const float* __restrict__ gamma,
                          const float* __restrict__ beta, float* __restrict__ out) {
  const float invn = 1.0f / 32768.f;
  int idx = blockIdx.x * 256 + threadIdx.x;   // 524288 threads
  const float4* hv = (const float4*)h;
  float4* ov = (float4*)out;
  for (int i = idx; i < 2097152; i += 524288) {
    int c4 = (i & 63) * 4;
    float4 v = hv[i];
    float4 g4 = *(const float4*)&gamma[c4];
    float4 b4 = *(const float4*)&beta[c4];
    float4 s4 = *(const float4*)&cs[c4];
    float4 q4 = *(const float4*)&cq[c4];
    float vi[4] = {v.x, v.y, v.z, v.w};
    float gi[4] = {g4.x, g4.y, g4.z, g4.w};
    float bi[4] = {b4.x, b4.y, b4.z, b4.w};
    float si[4] = {s4.x, s4.y, s4.z, s4.w};
    float qi[4] = {q4.x, q4.y, q4.z, q4.w};
    float oo[4];
#pragma unroll
    for (int c = 0; c < 4; c++) {
      float mu = si[c] * invn;
      float var = qi[c] * invn - mu * mu;
      float sc = gi[c] * rsqrtf(var + 1e-5f);
      float sh = bi[c] - mu * sc;
      oo[c] = fmaxf(fmaf(vi[c], sc, sh), 0.f);
    }
    float4 o4; o4.x = oo[0]; o4.y = oo[1]; o4.z = oo[2]; o4.w = oo[3];
    ov[i] = o4;
  }
}

// ---------------- row sums ----------------
__global__ void k_rowsum(const float* __restrict__ x, float* __restrict__ rs) {
  int w = (blockIdx.x * blockDim.x + threadIdx.x) >> 6;
  int lane = threadIdx.x & 63;
  float4 v = ((const float4*)x)[(size_t)w * 64 + lane];
  float s = v.x + v.y + v.z + v.w;
#pragma unroll
  for (int m = 1; m < 64; m <<= 1) s += __shfl_xor(s, m, 64);
  if (lane == 0) rs[w] = s;
}

__global__ void k_sumg1(const float* __restrict__ rs, float* __restrict__ sg) {
  int b = threadIdx.x;   // 128 threads
  float s = 0.f;
  for (int t = 0; t < 256; t++) s += rs[b * 256 + t];
  sg[b] = s;
}

// ---------------- fused scores + gumbel + sinkhorn + reduction ----------------
union ScoreSh {
  struct { float As[256][36]; float Bs[32][256]; } g;
  struct { float red[32][256]; float cmax[256]; float cstat[256]; } s;
};

__global__ __launch_bounds__(1024) void k_scores(
    const float* __restrict__ MW, const float* __restrict__ M2,
    const float* __restrict__ U, const float* __restrict__ rs2,
    const float* __restrict__ sg1, float* __restrict__ pout) {
  __shared__ ScoreSh sh;
  int tid = threadIdx.x;
  int u = tid >> 5, v = tid & 31;
  int b = blockIdx.x;
  const float* A = MW + (size_t)b * 65536;
  const float* Bm = M2 + (size_t)b * 65536;

  // rows s = u + 32*i (i 0..7); cols t = v*4 + 128*jj + c (jj 0..1, c 0..3)
  float la[8][8];
#pragma unroll
  for (int i = 0; i < 8; i++)
#pragma unroll
    for (int c = 0; c < 8; c++) la[i][c] = 0.f;

  for (int k0 = 0; k0 < 256; k0 += 32) {
#pragma unroll
    for (int it = 0; it < 2; it++) {
      int fid = tid + it * 1024;
      int sI = fid & 255, kg = (fid >> 8) * 4;
      float4 va = *(const float4*)&A[(size_t)sI * 256 + k0 + kg];
      *(float4*)&sh.g.As[sI][kg] = va;
      float4 vb = *(const float4*)&Bm[(size_t)sI * 256 + k0 + kg];
      sh.g.Bs[kg + 0][sI] = vb.x; sh.g.Bs[kg + 1][sI] = vb.y;
      sh.g.Bs[kg + 2][sI] = vb.z; sh.g.Bs[kg + 3][sI] = vb.w;
    }
    __syncthreads();
#pragma unroll
    for (int kk = 0; kk < 32; kk += 4) {
      float afv[8][4];
#pragma unroll
      for (int i = 0; i < 8; i++) {
        float4 t4 = *(const float4*)&sh.g.As[u + 32 * i][kk];
        afv[i][0] = t4.x; afv[i][1] = t4.y; afv[i][2] = t4.z; afv[i][3] = t4.w;
      }
#pragma unroll
      for (int dk = 0; dk < 4; dk++) {
        float4 b0 = *(const float4*)&sh.g.Bs[kk + dk][v * 4];
        float4 b1 = *(const float4*)&sh.g.Bs[kk + dk][v * 4 + 128];
        float bb[8] = {b0.x, b0.y, b0.z, b0.w, b1.x, b1.y, b1.z, b1.w};
#pragma unroll
        for (int i = 0; i < 8; i++) {
          float a = afv[i][dk];
#pragma unroll
          for (int c = 0; c < 8; c++) la[i][c] = fmaf(a, bb[c], la[i][c]);
        }
      }
    }
    __syncthreads();
  }

  // gumbel + /TAU
#pragma unroll
  for (int i = 0; i < 8; i++) {
    int sI = u + 32 * i;
#pragma unroll
    for (int jj = 0; jj < 2; jj++) {
      float4 u4 = *(const float4*)&U[(size_t)b * 65536 + (size_t)sI * 256 + v * 4 + 128 * jj];
      float uu[4] = {u4.x, u4.y, u4.z, u4.w};
#pragma unroll
      for (int c = 0; c < 4; c++) {
        float g = -__logf(-__logf(uu[c] + 1e-20f) + 1e-20f);
        la[i][jj * 4 + c] = (la[i][jj * 4 + c] + g) * 10.0f;   // 1/TAU
      }
    }
  }

  for (int iter = 0; iter < 20; iter++) {
    // ---- row logsumexp (over t), per row s: reduce across v (32 lanes, in-wave)
#pragma unroll
    for (int i = 0; i < 8; i++) {
      float m = la[i][0];
#pragma unroll
      for (int c = 1; c < 8; c++) m = fmaxf(m, la[i][c]);
#pragma unroll
      for (int msk = 1; msk < 32; msk <<= 1) m = fmaxf(m, __shfl_xor(m, msk, 64));
      float s = 0.f;
#pragma unroll
      for (int c = 0; c < 8; c++) s += __expf(la[i][c] - m);
#pragma unroll
      for (int msk = 1; msk < 32; msk <<= 1) s += __shfl_xor(s, msk, 64);
      float l = m + __logf(s);
#pragma unroll
      for (int c = 0; c < 8; c++) la[i][c] -= l;
    }
    // ---- col logsumexp (over s): LDS partials across u
    float cm[8];
#pragma unroll
    for (int c = 0; c < 8; c++) {
      float m = la[0][c];
#pragma unroll
      for (int i = 1; i < 8; i++) m = fmaxf(m, la[i][c]);
      cm[c] = m;
    }
    __syncthreads();
#pragma unroll
    for (int jj = 0; jj < 2; jj++) {
      float4 w4; w4.x = cm[jj * 4 + 0]; w4.y = cm[jj * 4 + 1]; w4.z = cm[jj * 4 + 2]; w4.w = cm[jj * 4 + 3];
      *(float4*)&sh.s.red[u][v * 4 + 128 * jj] = w4;
    }
    __syncthreads();
    if (tid < 256) {
      float m = -1e30f;
#pragma unroll
      for (int q = 0; q < 32; q++) m = fmaxf(m, sh.s.red[q][tid]);
      sh.s.cmax[tid] = m;
    }
    __syncthreads();
    float cmv[8];
#pragma unroll
    for (int jj = 0; jj < 2; jj++) {
      float4 c4 = *(const float4*)&sh.s.cmax[v * 4 + 128 * jj];
      cmv[jj * 4 + 0] = c4.x; cmv[jj * 4 + 1] = c4.y; cmv[jj * 4 + 2] = c4.z; cmv[jj * 4 + 3] = c4.w;
    }
    float se[8];
#pragma unroll
    for (int c = 0; c < 8; c++) {
      float s = 0.f;
#pragma unroll
      for (int i = 0; i < 8; i++) s += __expf(la[i][c] - cmv[c]);
      se[c] = s;
    }
#pragma unroll
    for (int jj = 0; jj < 2; jj++) {
      float4 w4; w4.x = se[jj * 4 + 0]; w4.y = se[jj * 4 + 1]; w4.z = se[jj * 4 + 2]; w4.w = se[jj * 4 + 3];
      *(float4*)&sh.s.red[u][v * 4 + 128 * jj] = w4;
    }
    __syncthreads();
    if (tid < 256) {
      float s = 0.f;
#pragma unroll
      for (int q = 0; q < 32; q++) s += sh.s.red[q][tid];
      sh.s.cstat[tid] = sh.s.cmax[tid] + __logf(s);
    }
    __syncthreads();
#pragma unroll
    for (int jj = 0; jj < 2; jj++) {
      float4 l4 = *(const float4*)&sh.s.cstat[v * 4 + 128 * jj];
      float li[4] = {l4.x, l4.y, l4.z, l4.w};
#pragma unroll
      for (int i = 0; i < 8; i++)
#pragma unroll
        for (int c = 0; c < 4; c++) la[i][jj * 4 + c] -= li[c];
    }
  }

  // colsum of P = exp(la), then p_b = sum(g1_b) - dot(colsumP, rowsum_g2_b)
  float cp[8];
#pragma unroll
  for (int c = 0; c < 8; c++) {
    float s = 0.f;
#pragma unroll
    for (int i = 0; i < 8; i++) s += __expf(la[i][c]);
    cp[c] = s;
  }
  __syncthreads();
#pragma unroll
  for (int jj = 0; jj < 2; jj++) {
    float4 w4; w4.x = cp[jj * 4 + 0]; w4.y = cp[jj * 4 + 1]; w4.z = cp[jj * 4 + 2]; w4.w = cp[jj * 4 + 3];
    *(float4*)&sh.s.red[u][v * 4 + 128 * jj] = w4;
  }
  __syncthreads();
  if (tid < 256) {
    float s = 0.f;
#pragma unroll
    for (int q = 0; q < 32; q++) s += sh.s.red[q][tid];
    sh.s.cstat[tid] = s * rs2[(size_t)b * 256 + tid];
  }
  __syncthreads();
  if (tid < 64) {
    float s = sh.s.cstat[tid] + sh.s.cstat[tid + 64] + sh.s.cstat[tid + 128] + sh.s.cstat[tid + 192];
#pragma unroll
    for (int msk = 1; msk < 64; msk <<= 1) s += __shfl_xor(s, msk, 64);
    if (tid == 0) pout[b] = sg1[b] - s;
  }
}

// ---------------- final normalize ----------------
__global__ void k_final(const float* __restrict__ p, float* __restrict__ out) {
  int t = threadIdx.x;   // 64 threads
  float a = p[t], b = p[t + 64];
  float mn = fminf(a, b), mx = fmaxf(a, b);
#pragma unroll
  for (int msk = 1; msk < 64; msk <<= 1) {
    mn = fminf(mn, __shfl_xor(mn, msk, 64));
    mx = fmaxf(mx, __shfl_xor(mx, msk, 64));
  }
  float inv = 1.0f / (mx - mn);
  out[t] = __expf(-(a - mn) * inv);
  out[t + 64] = __expf(-(b - mn) * inv);
}

// ---------------- host ----------------
extern "C" void kernel_launch(void* const* d_in, const int* in_sizes, int n_in,
                              void* d_out, int out_size, void* d_ws, size_t ws_size,
                              hipStream_t stream) {
  (void)in_sizes; (void)n_in; (void)out_size; (void)ws_size;
  const float* f1 = (const float*)d_in[0];
  const float* f2 = (const float*)d_in[1];
  const int* e1 = (const int*)d_in[2];
  const int* e2 = (const int*)d_in[3];
  const float* un = (const float*)d_in[4];
  const float* gw1 = (const float*)d_in[5];
  const float* gb1 = (const float*)d_in[6];
  const float* gw2 = (const float*)d_in[7];
  const float* gb2 = (const float*)d_in[8];
  const float* gga = (const float*)d_in[9];
  const float* gbe = (const float*)d_in[10];
  const float* fc1w = (const float*)d_in[11];
  const float* fc1b = (const float*)d_in[12];
  const float* fc2w = (const float*)d_in[13];
  const float* fc2b = (const float*)d_in[14];
  const float* Wb = (const float*)d_in[15];
  float* out = (float*)d_out;

  float* ws = (float*)d_ws;
  size_t o = 0;
  auto alloc = [&](size_t n) { float* p = ws + o; o += (n + 63) & ~(size_t)63; return p; };
  const size_t ND = (size_t)NNODE * 256;
  float* X1 = alloc(ND); float* P1 = alloc(ND); float* Q1 = alloc(ND);
  float* X2 = alloc(ND); float* P2 = alloc(ND); float* Q2 = alloc(ND);
  float* rs1 = alloc(NNODE); float* rs2 = alloc(NNODE);
  float* sg1 = alloc(128); float* pvec = alloc(128);
  float* colsum = alloc(256); float* colsq = alloc(256);   // contiguous pair
  int* cnt1 = (int*)alloc(NNODE); int* off1 = (int*)alloc(NNODE + 64);
  int* cur1 = (int*)alloc(NNODE); int* srcs1 = (int*)alloc(NEDGE);
  int* cnt2 = (int*)alloc(NNODE); int* off2 = (int*)alloc(NNODE + 64);
  int* cur2 = (int*)alloc(NNODE); int* srcs2 = (int*)alloc(NEDGE);

  // CSR build (edges are layer-invariant)
  hipMemsetAsync(cnt1, 0, NNODE * 4, stream);
  hipMemsetAsync(cnt2, 0, NNODE * 4, stream);
  k_degree<<<NEDGE / 256, 256, 0, stream>>>(e1 + NEDGE, cnt1);
  k_degree<<<NEDGE / 256, 256, 0, stream>>>(e2 + NEDGE, cnt2);
  k_scan<<<1, 1024, 0, stream>>>(cnt1, off1, cur1);
  k_scan<<<1, 1024, 0, stream>>>(cnt2, off2, cur2);
  k_scatter<<<NEDGE / 256, 256, 0, stream>>>(e1, e1 + NEDGE, cur1, srcs1);
  k_scatter<<<NEDGE / 256, 256, 0, stream>>>(e2, e2 + NEDGE, cur2, srcs2);

  const float* xin[2] = {f1, f2};
  float* X[2] = {X1, X2}; float* P[2] = {P1, P2}; float* Q[2] = {Q1, Q2};
  const int* OFF[2] = {off1, off2}; const int* SR[2] = {srcs1, srcs2};

  for (int l = 0; l < 3; l++) {
    for (int sd = 0; sd < 2; sd++) {
      const float* xc = (l == 0) ? xin[sd] : X[sd];
      k_aggregate<<<8192, 256, 0, stream>>>(xc, OFF[sd], SR[sd], P[sd]);
      k_gemm<1, true><<<256, 256, 0, stream>>>(P[sd], gw1 + l * 65536, gb1 + l * 256, Q[sd], nullptr, nullptr);
      hipMemsetAsync(colsum, 0, 512 * 4, stream);
      k_gemm<2, true><<<256, 256, 0, stream>>>(Q[sd], gw2 + l * 65536, gb2 + l * 256, P[sd], colsum, colsq);
      k_bnapply<<<2048, 256, 0, stream>>>(P[sd], colsum, colsq, gga + l * 256, gbe + l * 256, X[sd]);
    }
  }

  // sums of GIN outputs (needed for p = sum(g1) - colsumP . rowsum(g2))
  k_rowsum<<<8192, 256, 0, stream>>>(X1, rs1);
  k_rowsum<<<8192, 256, 0, stream>>>(X2, rs2);
  k_sumg1<<<1, 128, 0, stream>>>(rs1, sg1);

  // fc transforms
  k_gemm<1, true><<<256, 256, 0, stream>>>(X1, fc1w, fc1b, Q1, nullptr, nullptr);
  k_gemm<0, true><<<256, 256, 0, stream>>>(Q1, fc2w, fc2b, P1, nullptr, nullptr);
  k_gemm<0, false><<<256, 256, 0, stream>>>(P1, Wb, nullptr, Q1, nullptr, nullptr);   // mW = m1 @ W
  k_gemm<1, true><<<256, 256, 0, stream>>>(X2, fc1w, fc1b, Q2, nullptr, nullptr);
  k_gemm<0, true><<<256, 256, 0, stream>>>(Q2, fc2w, fc2b, P2, nullptr, nullptr);     // m2

  // fused scores + sinkhorn + reduction, one block per graph
  k_scores<<<128, 1024, 0, stream>>>(Q1, P2, un, rs2, sg1, pvec);
  k_final<<<1, 64, 0, stream>>>(pvec, out);
}

// Round 2
// 1457.758 us; speedup vs baseline: 1.4297x; 1.4297x over previous
//
#include <hip/hip_runtime.h>

// GSModel fused pipeline, round 2.
// KEY SIMPLIFICATION: sinkhorn ends with a column normalization, so colsum(P)==1
// exactly => p_b = sum(g1_b) - sum(g2_b). The scores GEMM, W, fc transforms,
// gumbel noise and all 20 sinkhorn iterations are dead code and are removed.
// Remaining pipeline: CSR build + 3x2 GIN layers (aggregate, 2 GEMMs w/ fused
// BN stats, BN apply) + per-graph sums + min-max normalize + exp.

constexpr int NNODE = 32768;
constexpr int NEDGE = 524288;

// ---------------- CSR build ----------------
__global__ void k_degree(const int* __restrict__ dst, int* __restrict__ cnt) {
  int e = blockIdx.x * 256 + threadIdx.x;
  atomicAdd(&cnt[dst[e]], 1);
}

__global__ void k_scan(const int* __restrict__ cnt, int* __restrict__ off, int* __restrict__ cur) {
  __shared__ int sh[1024];
  int t = threadIdx.x;
  int base = t * 32;
  int loc[32];
  int s = 0;
#pragma unroll
  for (int j = 0; j < 32; j++) { loc[j] = cnt[base + j]; s += loc[j]; }
  sh[t] = s;
  __syncthreads();
  for (int d = 1; d < 1024; d <<= 1) {
    int v = (t >= d) ? sh[t - d] : 0;
    __syncthreads();
    sh[t] += v;
    __syncthreads();
  }
  int run = sh[t] - s;
#pragma unroll
  for (int j = 0; j < 32; j++) { off[base + j] = run; cur[base + j] = run; run += loc[j]; }
  if (t == 1023) off[NNODE] = run;
}

__global__ void k_scatter(const int* __restrict__ src, const int* __restrict__ dst,
                          int* __restrict__ cur, int* __restrict__ srcs) {
  int e = blockIdx.x * 256 + threadIdx.x;
  int d = dst[e];
  int p = atomicAdd(&cur[d], 1);
  srcs[p] = src[e];
}

// ---------------- aggregate: out = (1+eps)*x + segment_sum, eps=1 ----------------
__global__ void k_aggregate(const float* __restrict__ x, const int* __restrict__ off,
                            const int* __restrict__ srcs, float* __restrict__ out) {
  int w = (blockIdx.x * blockDim.x + threadIdx.x) >> 6;   // node id (wave per node)
  int lane = threadIdx.x & 63;
  const float4* xv = (const float4*)x;
  float4 a = xv[(size_t)w * 64 + lane];
  float ax = 2.f * a.x, ay = 2.f * a.y, az = 2.f * a.z, aw = 2.f * a.w;
  int e0 = off[w], e1 = off[w + 1];
  for (int e = e0; e < e1; e++) {
    int sI = srcs[e];
    float4 v = xv[(size_t)sI * 64 + lane];
    ax += v.x; ay += v.y; az += v.z; aw += v.w;
  }
  float4 r; r.x = ax; r.y = ay; r.z = az; r.w = aw;
  ((float4*)out)[(size_t)w * 64 + lane] = r;
}

// ---------------- GEMM: C[32768x256] = A[32768x256] @ Wm[256x256] (+bias) ----------------
// EPI: 0 = plain, 1 = relu, 2 = plain + column sum/sumsq stats (for BatchNorm)
template <int EPI, bool HASB>
__global__ __launch_bounds__(256) void k_gemm(
    const float* __restrict__ A, const float* __restrict__ Wm,
    const float* __restrict__ bias, float* __restrict__ C,
    float* __restrict__ colsum, float* __restrict__ colsq) {
  __shared__ float As[128][36];   // rows x K-chunk, pad 36 to dodge bank conflicts
  __shared__ float Ws[32][256];   // K-chunk x N
  int tid = threadIdx.x;
  int tx = tid & 15, ty = tid >> 4;
  int m0 = blockIdx.x * 128;

  float acc[8][16];
#pragma unroll
  for (int r = 0; r < 8; r++)
#pragma unroll
    for (int c = 0; c < 16; c++) acc[r][c] = 0.f;

  for (int k0 = 0; k0 < 256; k0 += 32) {
#pragma unroll
    for (int it = 0; it < 4; it++) {
      int fid = tid + it * 256;
      int row = fid >> 3, cg = (fid & 7) * 4;
      float4 v = *(const float4*)&A[(size_t)(m0 + row) * 256 + k0 + cg];
      *(float4*)&As[row][cg] = v;
    }
#pragma unroll
    for (int it = 0; it < 8; it++) {
      int fid = tid + it * 256;
      int kr = fid >> 6, cg = (fid & 63) * 4;
      float4 v = *(const float4*)&Wm[(size_t)(k0 + kr) * 256 + cg];
      *(float4*)&Ws[kr][cg] = v;
    }
    __syncthreads();
#pragma unroll
    for (int kk = 0; kk < 32; kk += 4) {
      float afv[8][4];
#pragma unroll
      for (int r = 0; r < 8; r++) {
        float4 t4 = *(const float4*)&As[ty + 16 * r][kk];
        afv[r][0] = t4.x; afv[r][1] = t4.y; afv[r][2] = t4.z; afv[r][3] = t4.w;
      }
#pragma unroll
      for (int dk = 0; dk < 4; dk++) {
        float wf[4][4];
#pragma unroll
        for (int jj = 0; jj < 4; jj++) {
          float4 t4 = *(const float4*)&Ws[kk + dk][tx * 4 + 64 * jj];
          wf[jj][0] = t4.x; wf[jj][1] = t4.y; wf[jj][2] = t4.z; wf[jj][3] = t4.w;
        }
#pragma unroll
        for (int r = 0; r < 8; r++) {
          float a = afv[r][dk];
#pragma unroll
          for (int jj = 0; jj < 4; jj++) {
#pragma unroll
            for (int c = 0; c < 4; c++)
              acc[r][jj * 4 + c] = fmaf(a, wf[jj][c], acc[r][jj * 4 + c]);
          }
        }
      }
    }
    __syncthreads();
  }

  float bf[16];
#pragma unroll
  for (int jj = 0; jj < 4; jj++) {
    if (HASB) {
      float4 b4 = *(const float4*)&bias[tx * 4 + 64 * jj];
      bf[jj * 4 + 0] = b4.x; bf[jj * 4 + 1] = b4.y; bf[jj * 4 + 2] = b4.z; bf[jj * 4 + 3] = b4.w;
    } else {
      bf[jj * 4 + 0] = bf[jj * 4 + 1] = bf[jj * 4 + 2] = bf[jj * 4 + 3] = 0.f;
    }
  }

  float ps[16], pq[16];
  if constexpr (EPI == 2) {
#pragma unroll
    for (int c = 0; c < 16; c++) { ps[c] = 0.f; pq[c] = 0.f; }
  }

#pragma unroll
  for (int r = 0; r < 8; r++) {
    int row = m0 + ty + 16 * r;
#pragma unroll
    for (int jj = 0; jj < 4; jj++) {
      float v[4];
#pragma unroll
      for (int c = 0; c < 4; c++) {
        float o = acc[r][jj * 4 + c] + bf[jj * 4 + c];
        if constexpr (EPI == 1) o = fmaxf(o, 0.f);
        if constexpr (EPI == 2) { ps[jj * 4 + c] += o; pq[jj * 4 + c] += o * o; }
        v[c] = o;
      }
      float4 o4; o4.x = v[0]; o4.y = v[1]; o4.z = v[2]; o4.w = v[3];
      *(float4*)&C[(size_t)row * 256 + tx * 4 + 64 * jj] = o4;
    }
  }

  if constexpr (EPI == 2) {
    float* red = &Ws[0][0];   // reuse as [16][256]
#pragma unroll
    for (int jj = 0; jj < 4; jj++) {
      float4 w4; w4.x = ps[jj * 4 + 0]; w4.y = ps[jj * 4 + 1]; w4.z = ps[jj * 4 + 2]; w4.w = ps[jj * 4 + 3];
      *(float4*)&red[ty * 256 + tx * 4 + 64 * jj] = w4;
    }
    __syncthreads();
    if (tid < 256) {
      float s = 0.f;
#pragma unroll
      for (int q = 0; q < 16; q++) s += red[q * 256 + tid];
      atomicAdd(&colsum[tid], s);
    }
    __syncthreads();
#pragma unroll
    for (int jj = 0; jj < 4; jj++) {
      float4 w4; w4.x = pq[jj * 4 + 0]; w4.y = pq[jj * 4 + 1]; w4.z = pq[jj * 4 + 2]; w4.w = pq[jj * 4 + 3];
      *(float4*)&red[ty * 256 + tx * 4 + 64 * jj] = w4;
    }
    __syncthreads();
    if (tid < 256) {
      float s = 0.f;
#pragma unroll
      for (int q = 0; q < 16; q++) s += red[q * 256 + tid];
      atomicAdd(&colsq[tid], s);
    }
  }
}

// ---------------- BatchNorm apply + relu ----------------
__global__ void k_bnapply(const float* __restrict__ h, const float* __restrict__ cs,
                          const float* __restrict__ cq, const float* __restrict__ gamma,
                          const float* __restrict__ beta, float* __restrict__ out) {
  const float invn = 1.0f / 32768.f;
  int idx = blockIdx.x * 256 + threadIdx.x;   // 524288 threads
  const float4* hv = (const float4*)h;
  float4* ov = (float4*)out;
  for (int i = idx; i < 2097152; i += 524288) {
    int c4 = (i & 63) * 4;
    float4 v = hv[i];
    float4 g4 = *(const float4*)&gamma[c4];
    float4 b4 = *(const float4*)&beta[c4];
    float4 s4 = *(const float4*)&cs[c4];
    float4 q4 = *(const float4*)&cq[c4];
    float vi[4] = {v.x, v.y, v.z, v.w};
    float gi[4] = {g4.x, g4.y, g4.z, g4.w};
    float bi[4] = {b4.x, b4.y, b4.z, b4.w};
    float si[4] = {s4.x, s4.y, s4.z, s4.w};
    float qi[4] = {q4.x, q4.y, q4.z, q4.w};
    float oo[4];
#pragma unroll
    for (int c = 0; c < 4; c++) {
      float mu = si[c] * invn;
      float var = qi[c] * invn - mu * mu;
      float sc = gi[c] * rsqrtf(var + 1e-5f);
      float sh = bi[c] - mu * sc;
      oo[c] = fmaxf(fmaf(vi[c], sc, sh), 0.f);
    }
    float4 o4; o4.x = oo[0]; o4.y = oo[1]; o4.z = oo[2]; o4.w = oo[3];
    ov[i] = o4;
  }
}

// ---------------- per-graph sum of GIN output ----------------
__global__ __launch_bounds__(256) void k_graphsum(const float* __restrict__ x,
                                                  float* __restrict__ sg) {
  int b = blockIdx.x;          // 128 graphs
  int t = threadIdx.x;         // 256 threads
  const float4* xv = (const float4*)(x + (size_t)b * 65536);
  float s = 0.f;
  for (int i = t; i < 16384; i += 256) {
    float4 v = xv[i];
    s += v.x + v.y + v.z + v.w;
  }
  __shared__ float sh[256];
  sh[t] = s;
  __syncthreads();
  if (t < 64) {
    s = sh[t] + sh[t + 64] + sh[t + 128] + sh[t + 192];
#pragma unroll
    for (int m = 1; m < 64; m <<= 1) s += __shfl_xor(s, m, 64);
    if (t == 0) sg[b] = s;
  }
}

// ---------------- final: p = sg1 - sg2, min-max normalize, exp(-p) ----------------
__global__ void k_final(const float* __restrict__ sg1, const float* __restrict__ sg2,
                        float* __restrict__ out) {
  int t = threadIdx.x;   // 64 threads
  float a = sg1[t] - sg2[t];
  float b = sg1[t + 64] - sg2[t + 64];
  float mn = fminf(a, b), mx = fmaxf(a, b);
#pragma unroll
  for (int msk = 1; msk < 64; msk <<= 1) {
    mn = fminf(mn, __shfl_xor(mn, msk, 64));
    mx = fmaxf(mx, __shfl_xor(mx, msk, 64));
  }
  float inv = 1.0f / (mx - mn);
  out[t] = __expf(-(a - mn) * inv);
  out[t + 64] = __expf(-(b - mn) * inv);
}

// ---------------- host ----------------
extern "C" void kernel_launch(void* const* d_in, const int* in_sizes, int n_in,
                              void* d_out, int out_size, void* d_ws, size_t ws_size,
                              hipStream_t stream) {
  (void)in_sizes; (void)n_in; (void)out_size; (void)ws_size;
  const float* f1 = (const float*)d_in[0];
  const float* f2 = (const float*)d_in[1];
  const int* e1 = (const int*)d_in[2];
  const int* e2 = (const int*)d_in[3];
  const float* gw1 = (const float*)d_in[5];
  const float* gb1 = (const float*)d_in[6];
  const float* gw2 = (const float*)d_in[7];
  const float* gb2 = (const float*)d_in[8];
  const float* gga = (const float*)d_in[9];
  const float* gbe = (const float*)d_in[10];
  float* out = (float*)d_out;

  float* ws = (float*)d_ws;
  size_t o = 0;
  auto alloc = [&](size_t n) { float* p = ws + o; o += (n + 63) & ~(size_t)63; return p; };
  const size_t ND = (size_t)NNODE * 256;
  float* X1 = alloc(ND); float* P1 = alloc(ND); float* Q1 = alloc(ND);
  float* X2 = alloc(ND); float* P2 = alloc(ND); float* Q2 = alloc(ND);
  float* sg1 = alloc(128); float* sg2 = alloc(128);
  float* colsum = alloc(256); float* colsq = alloc(256);   // contiguous pair
  int* cnt1 = (int*)alloc(NNODE); int* off1 = (int*)alloc(NNODE + 64);
  int* cur1 = (int*)alloc(NNODE); int* srcs1 = (int*)alloc(NEDGE);
  int* cnt2 = (int*)alloc(NNODE); int* off2 = (int*)alloc(NNODE + 64);
  int* cur2 = (int*)alloc(NNODE); int* srcs2 = (int*)alloc(NEDGE);

  // CSR build (edges are layer-invariant)
  hipMemsetAsync(cnt1, 0, NNODE * 4, stream);
  hipMemsetAsync(cnt2, 0, NNODE * 4, stream);
  k_degree<<<NEDGE / 256, 256, 0, stream>>>(e1 + NEDGE, cnt1);
  k_degree<<<NEDGE / 256, 256, 0, stream>>>(e2 + NEDGE, cnt2);
  k_scan<<<1, 1024, 0, stream>>>(cnt1, off1, cur1);
  k_scan<<<1, 1024, 0, stream>>>(cnt2, off2, cur2);
  k_scatter<<<NEDGE / 256, 256, 0, stream>>>(e1, e1 + NEDGE, cur1, srcs1);
  k_scatter<<<NEDGE / 256, 256, 0, stream>>>(e2, e2 + NEDGE, cur2, srcs2);

  const float* xin[2] = {f1, f2};
  float* X[2] = {X1, X2}; float* P[2] = {P1, P2}; float* Q[2] = {Q1, Q2};
  const int* OFF[2] = {off1, off2}; const int* SR[2] = {srcs1, srcs2};

  for (int l = 0; l < 3; l++) {
    for (int sd = 0; sd < 2; sd++) {
      const float* xc = (l == 0) ? xin[sd] : X[sd];
      k_aggregate<<<8192, 256, 0, stream>>>(xc, OFF[sd], SR[sd], P[sd]);
      k_gemm<1, true><<<256, 256, 0, stream>>>(P[sd], gw1 + l * 65536, gb1 + l * 256, Q[sd], nullptr, nullptr);
      hipMemsetAsync(colsum, 0, 512 * 4, stream);
      k_gemm<2, true><<<256, 256, 0, stream>>>(Q[sd], gw2 + l * 65536, gb2 + l * 256, P[sd], colsum, colsq);
      k_bnapply<<<2048, 256, 0, stream>>>(P[sd], colsum, colsq, gga + l * 256, gbe + l * 256, X[sd]);
    }
  }

  // p_b = sum(g1_b) - sum(g2_b)  (colsum(P)==1 identity), then normalize
  k_graphsum<<<128, 256, 0, stream>>>(X1, sg1);
  k_graphsum<<<128, 256, 0, stream>>>(X2, sg2);
  k_final<<<1, 64, 0, stream>>>(sg1, sg2, out);
}

// Round 3
// 694.549 us; speedup vs baseline: 3.0006x; 2.0989x over previous
//
#include <hip/hip_runtime.h>

// GSModel pipeline, round 3: bf16 + MFMA.
//  - p_b = sum(g1_b) - sum(g2_b) identity (sinkhorn colsum==1) — scores path removed.
//  - bf16 storage everywhere: halves aggregate gather traffic (the top cost).
//  - Fused per-layer kernel: GEMM1(+bias,relu) -> LDS -> GEMM2(+bias) + BN-stats,
//    both sides in one launch (weights shared). mfma_f32_16x16x32_bf16,
//    XOR-swizzled LDS tiles (conflict-free), 112KB LDS, 512 thr (8 waves, 2x4).
//  - BN apply + relu folded into next aggregate / final graphsum (k_bnapply removed).

constexpr int NNODE = 32768;
constexpr int NEDGE = 524288;

typedef __attribute__((ext_vector_type(8))) short bf16x8;
typedef __attribute__((ext_vector_type(4))) float f32x4;

__device__ __forceinline__ float bf2f(unsigned short u) {
  return __uint_as_float((unsigned)u << 16);
}
__device__ __forceinline__ unsigned short f2bf(float f) {
  unsigned u = __float_as_uint(f);
  return (unsigned short)((u + 0x7FFFu + ((u >> 16) & 1u)) >> 16);
}

// ---------------- feature convert f32 -> bf16 ----------------
__global__ __launch_bounds__(256) void k_conv(const float* __restrict__ a,
                                              const float* __restrict__ b,
                                              unsigned short* __restrict__ out) {
  size_t i = (size_t)blockIdx.x * 256 + threadIdx.x;   // 4,194,304 chunks of 4
  const float* src = (i < 2097152) ? (a + i * 4) : (b + (i - 2097152) * 4);
  float4 v = *(const float4*)src;
  ushort4 o;
  o.x = f2bf(v.x); o.y = f2bf(v.y); o.z = f2bf(v.z); o.w = f2bf(v.w);
  *(ushort4*)(out + i * 4) = o;
}

// ---------------- weight transpose + convert: Wt[n][k] = W[k][n], bf16 ----------------
__global__ __launch_bounds__(256) void k_wprep(const float* __restrict__ gw1,
                                               const float* __restrict__ gw2,
                                               unsigned short* __restrict__ Wt) {
  __shared__ float sh[64][65];
  int b = blockIdx.x;            // 96 = 6 mats x 16 tiles of 64x64
  int mat = b >> 4, tile = b & 15;
  int tr = (tile >> 2) * 64, tc = (tile & 3) * 64;
  const float* src = (mat < 3) ? (gw1 + (size_t)mat * 65536) : (gw2 + (size_t)(mat - 3) * 65536);
  int t = threadIdx.x;
#pragma unroll
  for (int i = 0; i < 4; i++) {
    int c = t + i * 256;         // 1024 float4 chunks
    int row = c >> 4, c4 = (c & 15) * 4;
    float4 v = *(const float4*)(src + (size_t)(tr + row) * 256 + tc + c4);
    sh[row][c4] = v.x; sh[row][c4 + 1] = v.y; sh[row][c4 + 2] = v.z; sh[row][c4 + 3] = v.w;
  }
  __syncthreads();
#pragma unroll
  for (int i = 0; i < 2; i++) {
    int c = t + i * 256;         // 512 chunks of 8 bf16
    int n = c >> 3, kc = (c & 7) * 8;
    unsigned short e[8];
#pragma unroll
    for (int j = 0; j < 8; j++) e[j] = f2bf(sh[kc + j][n]);
    uint4 o;
    o.x = e[0] | ((unsigned)e[1] << 16);
    o.y = e[2] | ((unsigned)e[3] << 16);
    o.z = e[4] | ((unsigned)e[5] << 16);
    o.w = e[6] | ((unsigned)e[7] << 16);
    *(uint4*)(Wt + (size_t)mat * 65536 + (size_t)(tc + n) * 256 + tr + kc) = o;
  }
}

// ---------------- CSR build (both sides per launch) ----------------
__global__ void k_degree2(const int* __restrict__ e1, const int* __restrict__ e2,
                          int* __restrict__ cnt) {
  int b = blockIdx.x;                 // 4096
  int side = b >> 11;
  int e = (b & 2047) * 256 + threadIdx.x;
  const int* dst = (side ? e2 : e1) + NEDGE;
  atomicAdd(&cnt[side * NNODE + dst[e]], 1);
}

__global__ void k_scan2(const int* __restrict__ cnt, int* __restrict__ off,
                        int* __restrict__ cur) {
  __shared__ int sh[1024];
  int side = blockIdx.x;              // grid 2
  const int* c = cnt + side * NNODE;
  int* of = off + side * (NNODE + 64);
  int* cu = cur + side * NNODE;
  int t = threadIdx.x;
  int base = t * 32;
  int loc[32];
  int s = 0;
#pragma unroll
  for (int j = 0; j < 32; j++) { loc[j] = c[base + j]; s += loc[j]; }
  sh[t] = s;
  __syncthreads();
  for (int d = 1; d < 1024; d <<= 1) {
    int v = (t >= d) ? sh[t - d] : 0;
    __syncthreads();
    sh[t] += v;
    __syncthreads();
  }
  int run = sh[t] - s;
#pragma unroll
  for (int j = 0; j < 32; j++) { of[base + j] = run; cu[base + j] = run; run += loc[j]; }
  if (t == 1023) of[NNODE] = run;
}

__global__ void k_scatter2(const int* __restrict__ e1, const int* __restrict__ e2,
                           int* __restrict__ cur, int* __restrict__ srcs) {
  int b = blockIdx.x;                 // 4096
  int side = b >> 11;
  int e = (b & 2047) * 256 + threadIdx.x;
  const int* ei = (side ? e2 : e1);
  int d = ei[NEDGE + e];
  int p = atomicAdd(&cur[side * NNODE + d], 1);
  srcs[side * NEDGE + p] = ei[e];
}

// ---------------- aggregate: out = 2*x + segsum(x), x = (BN? relu(bn(h)) : h) ----------------
template <bool BN>
__global__ __launch_bounds__(256) void k_agg(
    const unsigned short* __restrict__ x,    // [2][NNODE][256] bf16
    const int* __restrict__ off, const int* __restrict__ srcs,
    const float* __restrict__ stats,         // [2][2][256] for prev layer (BN only)
    const float* __restrict__ gamma, const float* __restrict__ beta,
    unsigned short* __restrict__ out) {
  int w = (blockIdx.x * 256 + threadIdx.x) >> 6;   // wave per node, 65536 waves
  int side = w >> 15, n = w & 32767;
  int lane = threadIdx.x & 63;
  float sc0 = 1.f, sc1 = 1.f, sc2 = 1.f, sc3 = 1.f;
  float sh0 = 0.f, sh1 = 0.f, sh2 = 0.f, sh3 = 0.f;
  if (BN) {
    const float* cs = stats + side * 512;
    int c0 = lane * 4;
    float4 s4 = *(const float4*)(cs + c0);
    float4 q4 = *(const float4*)(cs + 256 + c0);
    float4 g4 = *(const float4*)(gamma + c0);
    float4 b4 = *(const float4*)(beta + c0);
    const float invn = 1.0f / 32768.f;
    float mu, var;
    mu = s4.x * invn; var = q4.x * invn - mu * mu; sc0 = g4.x * rsqrtf(var + 1e-5f); sh0 = b4.x - mu * sc0;
    mu = s4.y * invn; var = q4.y * invn - mu * mu; sc1 = g4.y * rsqrtf(var + 1e-5f); sh1 = b4.y - mu * sc1;
    mu = s4.z * invn; var = q4.z * invn - mu * mu; sc2 = g4.z * rsqrtf(var + 1e-5f); sh2 = b4.z - mu * sc2;
    mu = s4.w * invn; var = q4.w * invn - mu * mu; sc3 = g4.w * rsqrtf(var + 1e-5f); sh3 = b4.w - mu * sc3;
  }
  const ushort4* xv = (const ushort4*)x;
  size_t rbase = (size_t)side * NNODE;
  ushort4 a = xv[(rbase + n) * 64 + lane];
  float v0, v1, v2, v3;
#define LDX(u) do { \
    v0 = bf2f((u).x); v1 = bf2f((u).y); v2 = bf2f((u).z); v3 = bf2f((u).w); \
    if (BN) { \
      v0 = fmaxf(fmaf(v0, sc0, sh0), 0.f); v1 = fmaxf(fmaf(v1, sc1, sh1), 0.f); \
      v2 = fmaxf(fmaf(v2, sc2, sh2), 0.f); v3 = fmaxf(fmaf(v3, sc3, sh3), 0.f); \
    } } while (0)
  LDX(a);
  float ax = 2.f * v0, ay = 2.f * v1, az = 2.f * v2, aw = 2.f * v3;
  const int* offs = off + side * (NNODE + 64);
  const int* sr = srcs + (size_t)side * NEDGE;
  int e0 = offs[n], e1 = offs[n + 1];
  for (int e = e0; e < e1; e++) {
    ushort4 u = xv[(rbase + sr[e]) * 64 + lane];
    LDX(u);
    ax += v0; ay += v1; az += v2; aw += v3;
  }
#undef LDX
  ushort4 o;
  o.x = f2bf(ax); o.y = f2bf(ay); o.z = f2bf(az); o.w = f2bf(aw);
  ((ushort4*)out)[(rbase + n) * 64 + lane] = o;
}

// ---------------- fused GIN layer: h = (relu(Aggr@W1+b1))@W2 + b2, + BN stats ----------------
// grid 512 (2 sides x 256 row-blocks of 128), 512 threads = 8 waves (2m x 4n), wave tile 64x64.
__global__ __launch_bounds__(512) void k_gin(
    const unsigned short* __restrict__ Aggr,   // [2][N][256] bf16
    const unsigned short* __restrict__ w1t,    // [256][256] bf16, transposed
    const unsigned short* __restrict__ w2t,
    const float* __restrict__ b1, const float* __restrict__ b2,
    float* __restrict__ stats,                 // [2][2][256] this layer
    unsigned short* __restrict__ hout) {
  __shared__ __align__(16) char smem[114688];
  char* sA2 = smem;                // 64KB: intermediate [128 rows][512B], row-swizzled
  char* sA = smem + 65536;         // 16KB: A tile [128 rows][128B]
  char* sW = smem + 81920;         // 32KB: W tile [256 rows][128B]
  int tid = threadIdx.x;
  int lane = tid & 63, wid = tid >> 6;
  int wm = wid & 1, wn = wid >> 1;
  int q = lane >> 4, r = lane & 15;
  const int sw = (r & 7) << 4;
  int b = blockIdx.x;
  int side = b >> 8;
  size_t grow0 = (size_t)side * NNODE + (size_t)(b & 255) * 128;

  auto stageA = [&](int k0) {
    for (int c = tid; c < 1024; c += 512) {
      int row = c >> 3, cb = (c & 7) * 16;
      float4 v = *(const float4*)(Aggr + (grow0 + row) * 256 + k0 + (c & 7) * 8);
      *(float4*)(sA + row * 128 + (cb ^ ((row & 7) << 4))) = v;
    }
  };
  auto stageW = [&](const unsigned short* wsrc, int k0) {
    for (int c = tid; c < 2048; c += 512) {
      int row = c >> 3, cb = (c & 7) * 16;
      float4 v = *(const float4*)(wsrc + (size_t)row * 256 + k0 + (c & 7) * 8);
      *(float4*)(sW + row * 128 + (cb ^ ((row & 7) << 4))) = v;
    }
  };

  f32x4 acc[4][4];
#pragma unroll
  for (int mi = 0; mi < 4; mi++)
#pragma unroll
    for (int ni = 0; ni < 4; ni++) acc[mi][ni] = (f32x4){0.f, 0.f, 0.f, 0.f};

  // ---- phase 1: C1 = Aggr @ W1 ----
  for (int k0 = 0; k0 < 256; k0 += 64) {
    stageA(k0);
    stageW(w1t, k0);
    __syncthreads();
#pragma unroll
    for (int ks = 0; ks < 2; ks++) {
      bf16x8 af[4], bfr[4];
      int cb = (ks * 64 + q * 16) ^ sw;
#pragma unroll
      for (int mi = 0; mi < 4; mi++)
        af[mi] = *(const bf16x8*)(sA + (wm * 64 + mi * 16 + r) * 128 + cb);
#pragma unroll
      for (int ni = 0; ni < 4; ni++)
        bfr[ni] = *(const bf16x8*)(sW + (wn * 64 + ni * 16 + r) * 128 + cb);
#pragma unroll
      for (int mi = 0; mi < 4; mi++)
#pragma unroll
        for (int ni = 0; ni < 4; ni++)
          acc[mi][ni] = __builtin_amdgcn_mfma_f32_16x16x32_bf16(af[mi], bfr[ni], acc[mi][ni], 0, 0, 0);
    }
    __syncthreads();
  }

  // epilogue 1: bias + relu -> bf16 scatter into sA2 (row-swizzled)
  float b1v[4];
#pragma unroll
  for (int ni = 0; ni < 4; ni++) b1v[ni] = b1[wn * 64 + ni * 16 + r];
#pragma unroll
  for (int mi = 0; mi < 4; mi++)
#pragma unroll
    for (int ni = 0; ni < 4; ni++)
#pragma unroll
      for (int j = 0; j < 4; j++) {
        float o = fmaxf(acc[mi][ni][j] + b1v[ni], 0.f);
        int rowc = wm * 64 + mi * 16 + q * 4 + j;
        int colc = wn * 64 + ni * 16 + r;
        *(unsigned short*)(sA2 + rowc * 512 + ((colc * 2) ^ (((q * 4 + j) & 7) << 4))) = f2bf(o);
      }
#pragma unroll
  for (int mi = 0; mi < 4; mi++)
#pragma unroll
    for (int ni = 0; ni < 4; ni++) acc[mi][ni] = (f32x4){0.f, 0.f, 0.f, 0.f};
  __syncthreads();

  // ---- phase 2: C2 = relu(C1) @ W2 ----
  for (int k0 = 0; k0 < 256; k0 += 64) {
    stageW(w2t, k0);
    __syncthreads();
#pragma unroll
    for (int ks = 0; ks < 2; ks++) {
      bf16x8 af[4], bfr[4];
      int cbA = (k0 * 2 + ks * 64 + q * 16) ^ sw;
      int cbW = (ks * 64 + q * 16) ^ sw;
#pragma unroll
      for (int mi = 0; mi < 4; mi++)
        af[mi] = *(const bf16x8*)(sA2 + (wm * 64 + mi * 16 + r) * 512 + cbA);
#pragma unroll
      for (int ni = 0; ni < 4; ni++)
        bfr[ni] = *(const bf16x8*)(sW + (wn * 64 + ni * 16 + r) * 128 + cbW);
#pragma unroll
      for (int mi = 0; mi < 4; mi++)
#pragma unroll
        for (int ni = 0; ni < 4; ni++)
          acc[mi][ni] = __builtin_amdgcn_mfma_f32_16x16x32_bf16(af[mi], bfr[ni], acc[mi][ni], 0, 0, 0);
    }
    __syncthreads();
  }

  // epilogue 2: bias, BN stats (shfl + atomics), bf16 out via LDS bounce
  float b2v[4];
#pragma unroll
  for (int ni = 0; ni < 4; ni++) b2v[ni] = b2[wn * 64 + ni * 16 + r];
  float* cs = stats + side * 512;
#pragma unroll
  for (int ni = 0; ni < 4; ni++) {
    float ss = 0.f, sq = 0.f;
#pragma unroll
    for (int mi = 0; mi < 4; mi++)
#pragma unroll
      for (int j = 0; j < 4; j++) {
        float o = acc[mi][ni][j] + b2v[ni];
        acc[mi][ni][j] = o;
        ss += o; sq += o * o;
      }
    ss += __shfl_xor(ss, 16, 64); ss += __shfl_xor(ss, 32, 64);
    sq += __shfl_xor(sq, 16, 64); sq += __shfl_xor(sq, 32, 64);
    if (q == 0) {
      atomicAdd(&cs[wn * 64 + ni * 16 + r], ss);
      atomicAdd(&cs[256 + wn * 64 + ni * 16 + r], sq);
    }
  }
#pragma unroll
  for (int mi = 0; mi < 4; mi++)
#pragma unroll
    for (int ni = 0; ni < 4; ni++)
#pragma unroll
      for (int j = 0; j < 4; j++) {
        int rowc = wm * 64 + mi * 16 + q * 4 + j;
        int colc = wn * 64 + ni * 16 + r;
        *(unsigned short*)(sA2 + rowc * 512 + ((colc * 2) ^ (((q * 4 + j) & 7) << 4))) =
            f2bf(acc[mi][ni][j]);
      }
  __syncthreads();
  for (int c = tid; c < 4096; c += 512) {   // 128 rows x 32 chunks of 16B
    int row = c >> 5, cb = (c & 31) * 16;
    float4 v = *(const float4*)(sA2 + row * 512 + (cb ^ ((row & 7) << 4)));
    *(float4*)(hout + (grow0 + row) * 256 + (c & 31) * 8) = v;
  }
}

// ---------------- per-graph sum of relu(bn(h)) ----------------
__global__ __launch_bounds__(256) void k_gsum(
    const unsigned short* __restrict__ h, const float* __restrict__ stats,
    const float* __restrict__ gamma, const float* __restrict__ beta,
    float* __restrict__ sg) {
  int b = blockIdx.x;            // 256 = 2 sides x 128 graphs
  int side = b >> 7, g = b & 127;
  int t = threadIdx.x;
  int c0 = (t & 63) * 4, rg = t >> 6;
  const float* cs = stats + side * 512;
  float sc[4], sh_[4];
#pragma unroll
  for (int j = 0; j < 4; j++) {
    float mu = cs[c0 + j] * (1.f / 32768.f);
    float var = cs[256 + c0 + j] * (1.f / 32768.f) - mu * mu;
    float s = gamma[c0 + j] * rsqrtf(var + 1e-5f);
    sc[j] = s; sh_[j] = beta[c0 + j] - mu * s;
  }
  size_t base = (size_t)side * NNODE + (size_t)g * 256;
  float acc = 0.f;
  for (int k = 0; k < 64; k++) {
    int row = rg + k * 4;
    ushort4 u = *(const ushort4*)(h + (base + row) * 256 + c0);
    acc += fmaxf(fmaf(bf2f(u.x), sc[0], sh_[0]), 0.f);
    acc += fmaxf(fmaf(bf2f(u.y), sc[1], sh_[1]), 0.f);
    acc += fmaxf(fmaf(bf2f(u.z), sc[2], sh_[2]), 0.f);
    acc += fmaxf(fmaf(bf2f(u.w), sc[3], sh_[3]), 0.f);
  }
  __shared__ float red[256];
  red[t] = acc;
  __syncthreads();
  if (t < 64) {
    float s = red[t] + red[t + 64] + red[t + 128] + red[t + 192];
#pragma unroll
    for (int m = 1; m < 64; m <<= 1) s += __shfl_xor(s, m, 64);
    if (t == 0) sg[b] = s;
  }
}

// ---------------- final: p = sg1 - sg2, min-max normalize, exp(-p) ----------------
__global__ void k_final(const float* __restrict__ sg1, const float* __restrict__ sg2,
                        float* __restrict__ out) {
  int t = threadIdx.x;   // 64 threads
  float a = sg1[t] - sg2[t];
  float b = sg1[t + 64] - sg2[t + 64];
  float mn = fminf(a, b), mx = fmaxf(a, b);
#pragma unroll
  for (int msk = 1; msk < 64; msk <<= 1) {
    mn = fminf(mn, __shfl_xor(mn, msk, 64));
    mx = fmaxf(mx, __shfl_xor(mx, msk, 64));
  }
  float inv = 1.0f / (mx - mn);
  out[t] = __expf(-(a - mn) * inv);
  out[t + 64] = __expf(-(b - mn) * inv);
}

// ---------------- host ----------------
extern "C" void kernel_launch(void* const* d_in, const int* in_sizes, int n_in,
                              void* d_out, int out_size, void* d_ws, size_t ws_size,
                              hipStream_t stream) {
  (void)in_sizes; (void)n_in; (void)out_size; (void)ws_size;
  const float* f1 = (const float*)d_in[0];
  const float* f2 = (const float*)d_in[1];
  const int* e1 = (const int*)d_in[2];
  const int* e2 = (const int*)d_in[3];
  const float* gw1 = (const float*)d_in[5];
  const float* gb1 = (const float*)d_in[6];
  const float* gw2 = (const float*)d_in[7];
  const float* gb2 = (const float*)d_in[8];
  const float* gga = (const float*)d_in[9];
  const float* gbe = (const float*)d_in[10];
  float* out = (float*)d_out;

  char* ws = (char*)d_ws;
  size_t o = 0;
  auto alloc = [&](size_t bytes) { void* p = ws + o; o += (bytes + 255) & ~(size_t)255; return p; };
  unsigned short* hbuf = (unsigned short*)alloc(2ull * NNODE * 256 * 2);
  unsigned short* aggr = (unsigned short*)alloc(2ull * NNODE * 256 * 2);
  unsigned short* Wt = (unsigned short*)alloc(6ull * 65536 * 2);
  float* stats = (float*)alloc(3 * 1024 * 4);      // [layer][side][{sum,sq}][256]
  float* sg = (float*)alloc(256 * 4);
  int* cnt = (int*)alloc(2 * NNODE * 4);
  int* off = (int*)alloc(2 * (NNODE + 64) * 4);
  int* cur = (int*)alloc(2 * NNODE * 4);
  int* srcs = (int*)alloc(2ull * NEDGE * 4);

  hipMemsetAsync(stats, 0, 3 * 1024 * 4, stream);
  hipMemsetAsync(cnt, 0, 2 * NNODE * 4, stream);

  k_conv<<<16384, 256, 0, stream>>>(f1, f2, hbuf);
  k_wprep<<<96, 256, 0, stream>>>(gw1, gw2, Wt);
  k_degree2<<<4096, 256, 0, stream>>>(e1, e2, cnt);
  k_scan2<<<2, 1024, 0, stream>>>(cnt, off, cur);
  k_scatter2<<<4096, 256, 0, stream>>>(e1, e2, cur, srcs);

  for (int l = 0; l < 3; l++) {
    if (l == 0)
      k_agg<false><<<16384, 256, 0, stream>>>(hbuf, off, srcs, nullptr, nullptr, nullptr, aggr);
    else
      k_agg<true><<<16384, 256, 0, stream>>>(hbuf, off, srcs, stats + (l - 1) * 1024,
                                             gga + (l - 1) * 256, gbe + (l - 1) * 256, aggr);
    k_gin<<<512, 512, 0, stream>>>(aggr, Wt + (size_t)l * 65536, Wt + (size_t)(3 + l) * 65536,
                                   gb1 + l * 256, gb2 + l * 256, stats + l * 1024, hbuf);
  }

  k_gsum<<<256, 256, 0, stream>>>(hbuf, stats + 2 * 1024, gga + 512, gbe + 512, sg);
  k_final<<<1, 64, 0, stream>>>(sg, sg + 128, out);
}

// Round 4
// 552.459 us; speedup vs baseline: 3.7724x; 1.2572x over previous
//
#include <hip/hip_runtime.h>

// GSModel pipeline, round 4.
//  - p_b = sum(g1_b) - sum(g2_b) identity (sinkhorn colsum==1) — scores path removed.
//  - bf16 storage; fused GIN layer GEMMs (MFMA 16x16x32 bf16, swizzled LDS).
//  - k_agg v2: half-wave (32 lanes x 16B) per node row, 2 nodes/wave, BN fused with
//    per-lane precomputed scale/shift, edge loop unrolled x2 (2 gathers in flight).
//  - k_gin v2: 64-row tiles, 64KB LDS (sA aliased inside sA2) -> 2 blocks/CU.

constexpr int NNODE = 32768;
constexpr int NEDGE = 524288;

typedef __attribute__((ext_vector_type(8))) short bf16x8;
typedef __attribute__((ext_vector_type(4))) float f32x4;

__device__ __forceinline__ float bf2f(unsigned short u) {
  return __uint_as_float((unsigned)u << 16);
}
__device__ __forceinline__ unsigned short f2bf(float f) {
  unsigned u = __float_as_uint(f);
  return (unsigned short)((u + 0x7FFFu + ((u >> 16) & 1u)) >> 16);
}
__device__ __forceinline__ unsigned packbf(float a, float b) {
  return (unsigned)f2bf(a) | ((unsigned)f2bf(b) << 16);
}

// ---------------- feature convert f32 -> bf16 ----------------
__global__ __launch_bounds__(256) void k_conv(const float* __restrict__ a,
                                              const float* __restrict__ b,
                                              unsigned short* __restrict__ out) {
  size_t i = (size_t)blockIdx.x * 256 + threadIdx.x;   // 4,194,304 chunks of 4
  const float* src = (i < 2097152) ? (a + i * 4) : (b + (i - 2097152) * 4);
  float4 v = *(const float4*)src;
  ushort4 o;
  o.x = f2bf(v.x); o.y = f2bf(v.y); o.z = f2bf(v.z); o.w = f2bf(v.w);
  *(ushort4*)(out + i * 4) = o;
}

// ---------------- weight transpose + convert: Wt[n][k] = W[k][n], bf16 ----------------
__global__ __launch_bounds__(256) void k_wprep(const float* __restrict__ gw1,
                                               const float* __restrict__ gw2,
                                               unsigned short* __restrict__ Wt) {
  __shared__ float sh[64][65];
  int b = blockIdx.x;            // 96 = 6 mats x 16 tiles of 64x64
  int mat = b >> 4, tile = b & 15;
  int tr = (tile >> 2) * 64, tc = (tile & 3) * 64;
  const float* src = (mat < 3) ? (gw1 + (size_t)mat * 65536) : (gw2 + (size_t)(mat - 3) * 65536);
  int t = threadIdx.x;
#pragma unroll
  for (int i = 0; i < 4; i++) {
    int c = t + i * 256;         // 1024 float4 chunks
    int row = c >> 4, c4 = (c & 15) * 4;
    float4 v = *(const float4*)(src + (size_t)(tr + row) * 256 + tc + c4);
    sh[row][c4] = v.x; sh[row][c4 + 1] = v.y; sh[row][c4 + 2] = v.z; sh[row][c4 + 3] = v.w;
  }
  __syncthreads();
#pragma unroll
  for (int i = 0; i < 2; i++) {
    int c = t + i * 256;         // 512 chunks of 8 bf16
    int n = c >> 3, kc = (c & 7) * 8;
    unsigned short e[8];
#pragma unroll
    for (int j = 0; j < 8; j++) e[j] = f2bf(sh[kc + j][n]);
    uint4 o;
    o.x = e[0] | ((unsigned)e[1] << 16);
    o.y = e[2] | ((unsigned)e[3] << 16);
    o.z = e[4] | ((unsigned)e[5] << 16);
    o.w = e[6] | ((unsigned)e[7] << 16);
    *(uint4*)(Wt + (size_t)mat * 65536 + (size_t)(tc + n) * 256 + tr + kc) = o;
  }
}

// ---------------- CSR build (both sides per launch) ----------------
__global__ void k_degree2(const int* __restrict__ e1, const int* __restrict__ e2,
                          int* __restrict__ cnt) {
  int b = blockIdx.x;                 // 4096
  int side = b >> 11;
  int e = (b & 2047) * 256 + threadIdx.x;
  const int* dst = (side ? e2 : e1) + NEDGE;
  atomicAdd(&cnt[side * NNODE + dst[e]], 1);
}

__global__ void k_scan2(const int* __restrict__ cnt, int* __restrict__ off,
                        int* __restrict__ cur) {
  __shared__ int sh[1024];
  int side = blockIdx.x;              // grid 2
  const int* c = cnt + side * NNODE;
  int* of = off + side * (NNODE + 64);
  int* cu = cur + side * NNODE;
  int t = threadIdx.x;
  int base = t * 32;
  int loc[32];
  int s = 0;
#pragma unroll
  for (int j = 0; j < 32; j++) { loc[j] = c[base + j]; s += loc[j]; }
  sh[t] = s;
  __syncthreads();
  for (int d = 1; d < 1024; d <<= 1) {
    int v = (t >= d) ? sh[t - d] : 0;
    __syncthreads();
    sh[t] += v;
    __syncthreads();
  }
  int run = sh[t] - s;
#pragma unroll
  for (int j = 0; j < 32; j++) { of[base + j] = run; cu[base + j] = run; run += loc[j]; }
  if (t == 1023) of[NNODE] = run;
}

__global__ void k_scatter2(const int* __restrict__ e1, const int* __restrict__ e2,
                           int* __restrict__ cur, int* __restrict__ srcs) {
  int b = blockIdx.x;                 // 4096
  int side = b >> 11;
  int e = (b & 2047) * 256 + threadIdx.x;
  const int* ei = (side ? e2 : e1);
  int d = ei[NEDGE + e];
  int p = atomicAdd(&cur[side * NNODE + d], 1);
  srcs[side * NEDGE + p] = ei[e];
}

// ---------------- aggregate: out = 2*x' + segsum(x'), x' = (BN? relu(bn(h)) : h) ----------------
// half-wave (32 lanes x 16B) owns one node row; 2 nodes per wave.
template <bool BN>
__global__ __launch_bounds__(256) void k_agg(
    const unsigned short* __restrict__ x,    // [2*NNODE][256] bf16
    const int* __restrict__ off, const int* __restrict__ srcs,
    const float* __restrict__ stats,         // [2][2][256] prev layer (BN only)
    const float* __restrict__ gamma, const float* __restrict__ beta,
    unsigned short* __restrict__ out) {
  int wv = (blockIdx.x * 256 + threadIdx.x) >> 6;   // 0..32767
  int lane = threadIdx.x & 63;
  int half = lane >> 5, sub = lane & 31;
  int node = wv * 2 + half;                         // 0..65535
  int side = node >> 15, n = node & 32767;

  float sc[8], sh[8];
  if (BN) {
    const float* cs = stats + side * 512;
    int c0 = sub * 8;
    const float invn = 1.f / 32768.f;
#pragma unroll
    for (int h4 = 0; h4 < 2; h4++) {
      float4 s4 = *(const float4*)(cs + c0 + h4 * 4);
      float4 q4 = *(const float4*)(cs + 256 + c0 + h4 * 4);
      float4 g4 = *(const float4*)(gamma + c0 + h4 * 4);
      float4 b4 = *(const float4*)(beta + c0 + h4 * 4);
      float sv[4] = {s4.x, s4.y, s4.z, s4.w};
      float qv[4] = {q4.x, q4.y, q4.z, q4.w};
      float gv[4] = {g4.x, g4.y, g4.z, g4.w};
      float bv[4] = {b4.x, b4.y, b4.z, b4.w};
#pragma unroll
      for (int j = 0; j < 4; j++) {
        float mu = sv[j] * invn;
        float var = qv[j] * invn - mu * mu;
        float s = gv[j] * rsqrtf(var + 1e-5f);
        sc[h4 * 4 + j] = s;
        sh[h4 * 4 + j] = bv[j] - mu * s;
      }
    }
  }

  float acc[8];
#pragma unroll
  for (int j = 0; j < 8; j++) acc[j] = 0.f;

  auto accum = [&](uint4 u, float wgt) {
    float f[8];
    f[0] = __uint_as_float(u.x << 16); f[1] = __uint_as_float(u.x & 0xFFFF0000u);
    f[2] = __uint_as_float(u.y << 16); f[3] = __uint_as_float(u.y & 0xFFFF0000u);
    f[4] = __uint_as_float(u.z << 16); f[5] = __uint_as_float(u.z & 0xFFFF0000u);
    f[6] = __uint_as_float(u.w << 16); f[7] = __uint_as_float(u.w & 0xFFFF0000u);
#pragma unroll
    for (int j = 0; j < 8; j++) {
      float v = BN ? fmaxf(fmaf(f[j], sc[j], sh[j]), 0.f) : f[j];
      acc[j] = fmaf(v, wgt, acc[j]);
    }
  };

  const uint4* rows = (const uint4*)x;
  size_t rbase = (size_t)side * NNODE;
  // self * 2
  accum(rows[(size_t)node * 32 + sub], 2.f);

  const int* offs = off + side * (NNODE + 64);
  const int* sr = srcs + (size_t)side * NEDGE;
  int e = offs[n], eend = offs[n + 1];
  for (; e + 1 < eend; e += 2) {
    int ia = sr[e], ib = sr[e + 1];
    uint4 va = rows[(rbase + ia) * 32 + sub];
    uint4 vb = rows[(rbase + ib) * 32 + sub];
    accum(va, 1.f);
    accum(vb, 1.f);
  }
  if (e < eend) {
    int ia = sr[e];
    accum(rows[(rbase + ia) * 32 + sub], 1.f);
  }

  uint4 o;
  o.x = packbf(acc[0], acc[1]);
  o.y = packbf(acc[2], acc[3]);
  o.z = packbf(acc[4], acc[5]);
  o.w = packbf(acc[6], acc[7]);
  ((uint4*)out)[(size_t)node * 32 + sub] = o;
}

// ---------------- fused GIN layer: h = (relu(Aggr@W1+b1))@W2 + b2, + BN stats ----------------
// grid 1024 (2 sides x 512 row-blocks of 64), 512 thr = 8 waves (2m x 4n), wave tile 32x64.
// LDS 64KB: sA2 [64][512B] at [0,32K) (sA [64][128B] aliased at [0,8K)), sW [256][128B] at [32K,64K).
__global__ __launch_bounds__(512) void k_gin(
    const unsigned short* __restrict__ Aggr,   // [2*N][256] bf16
    const unsigned short* __restrict__ w1t,    // [256][256] bf16, transposed
    const unsigned short* __restrict__ w2t,
    const float* __restrict__ b1, const float* __restrict__ b2,
    float* __restrict__ stats,                 // [2][2][256] this layer
    unsigned short* __restrict__ hout) {
  __shared__ __align__(16) char smem[65536];
  char* sA2 = smem;                // 32KB
  char* sA = smem;                 // 8KB alias (phase1 only)
  char* sW = smem + 32768;         // 32KB
  int tid = threadIdx.x;
  int lane = tid & 63, wid = tid >> 6;
  int wm = wid & 1, wn = wid >> 1;
  int q = lane >> 4, r = lane & 15;
  const int sw = (r & 7) << 4;
  int b = blockIdx.x;
  int side = b >> 9;
  size_t grow0 = (size_t)side * NNODE + (size_t)(b & 511) * 64;

  auto stageA = [&](int k0) {
    int c = tid;                   // 512 chunks of 16B: 64 rows x 8
    int row = c >> 3, cb = (c & 7) * 16;
    float4 v = *(const float4*)(Aggr + (grow0 + row) * 256 + k0 + (c & 7) * 8);
    *(float4*)(sA + row * 128 + (cb ^ ((row & 7) << 4))) = v;
  };
  auto stageW = [&](const unsigned short* wsrc, int k0) {
    for (int c = tid; c < 2048; c += 512) {
      int row = c >> 3, cb = (c & 7) * 16;
      float4 v = *(const float4*)(wsrc + (size_t)row * 256 + k0 + (c & 7) * 8);
      *(float4*)(sW + row * 128 + (cb ^ ((row & 7) << 4))) = v;
    }
  };

  f32x4 acc[2][4];
#pragma unroll
  for (int mi = 0; mi < 2; mi++)
#pragma unroll
    for (int ni = 0; ni < 4; ni++) acc[mi][ni] = (f32x4){0.f, 0.f, 0.f, 0.f};

  // ---- phase 1: C1 = Aggr @ W1 ----
  for (int k0 = 0; k0 < 256; k0 += 64) {
    stageA(k0);
    stageW(w1t, k0);
    __syncthreads();
#pragma unroll
    for (int ks = 0; ks < 2; ks++) {
      bf16x8 af[2], bfr[4];
      int cb = (ks * 64 + q * 16) ^ sw;
#pragma unroll
      for (int mi = 0; mi < 2; mi++)
        af[mi] = *(const bf16x8*)(sA + (wm * 32 + mi * 16 + r) * 128 + cb);
#pragma unroll
      for (int ni = 0; ni < 4; ni++)
        bfr[ni] = *(const bf16x8*)(sW + (wn * 64 + ni * 16 + r) * 128 + cb);
#pragma unroll
      for (int mi = 0; mi < 2; mi++)
#pragma unroll
        for (int ni = 0; ni < 4; ni++)
          acc[mi][ni] = __builtin_amdgcn_mfma_f32_16x16x32_bf16(af[mi], bfr[ni], acc[mi][ni], 0, 0, 0);
    }
    __syncthreads();
  }

  // epilogue 1: bias + relu -> bf16 into sA2 (row-swizzled)
  float b1v[4];
#pragma unroll
  for (int ni = 0; ni < 4; ni++) b1v[ni] = b1[wn * 64 + ni * 16 + r];
#pragma unroll
  for (int mi = 0; mi < 2; mi++)
#pragma unroll
    for (int ni = 0; ni < 4; ni++)
#pragma unroll
      for (int j = 0; j < 4; j++) {
        float o = fmaxf(acc[mi][ni][j] + b1v[ni], 0.f);
        int rowc = wm * 32 + mi * 16 + q * 4 + j;
        int colc = wn * 64 + ni * 16 + r;
        *(unsigned short*)(sA2 + rowc * 512 + ((colc * 2) ^ (((q * 4 + j) & 7) << 4))) = f2bf(o);
      }
#pragma unroll
  for (int mi = 0; mi < 2; mi++)
#pragma unroll
    for (int ni = 0; ni < 4; ni++) acc[mi][ni] = (f32x4){0.f, 0.f, 0.f, 0.f};
  __syncthreads();

  // ---- phase 2: C2 = relu(C1) @ W2 ----
  for (int k0 = 0; k0 < 256; k0 += 64) {
    stageW(w2t, k0);
    __syncthreads();
#pragma unroll
    for (int ks = 0; ks < 2; ks++) {
      bf16x8 af[2], bfr[4];
      int cbW = (ks * 64 + q * 16) ^ sw;
#pragma unroll
      for (int mi = 0; mi < 2; mi++) {
        int cbA = (k0 * 2 + ks * 64 + q * 16) ^ sw;
        af[mi] = *(const bf16x8*)(sA2 + (wm * 32 + mi * 16 + r) * 512 + cbA);
      }
#pragma unroll
      for (int ni = 0; ni < 4; ni++)
        bfr[ni] = *(const bf16x8*)(sW + (wn * 64 + ni * 16 + r) * 128 + cbW);
#pragma unroll
      for (int mi = 0; mi < 2; mi++)
#pragma unroll
        for (int ni = 0; ni < 4; ni++)
          acc[mi][ni] = __builtin_amdgcn_mfma_f32_16x16x32_bf16(af[mi], bfr[ni], acc[mi][ni], 0, 0, 0);
    }
    __syncthreads();
  }

  // epilogue 2: bias, BN stats (shfl + LDS cross-wave reduce + atomics), bf16 out
  float b2v[4];
#pragma unroll
  for (int ni = 0; ni < 4; ni++) b2v[ni] = b2[wn * 64 + ni * 16 + r];
  float2* red = (float2*)sW;       // [256 cols][2 wm] — sW dead after phase 2
#pragma unroll
  for (int ni = 0; ni < 4; ni++) {
    float ss = 0.f, sq = 0.f;
#pragma unroll
    for (int mi = 0; mi < 2; mi++)
#pragma unroll
      for (int j = 0; j < 4; j++) {
        float o = acc[mi][ni][j] + b2v[ni];
        acc[mi][ni][j] = o;
        ss += o; sq += o * o;
      }
    ss += __shfl_xor(ss, 16, 64); ss += __shfl_xor(ss, 32, 64);
    sq += __shfl_xor(sq, 16, 64); sq += __shfl_xor(sq, 32, 64);
    if (q == 0) {
      float2 w; w.x = ss; w.y = sq;
      red[(wn * 64 + ni * 16 + r) * 2 + wm] = w;
    }
  }
#pragma unroll
  for (int mi = 0; mi < 2; mi++)
#pragma unroll
    for (int ni = 0; ni < 4; ni++)
#pragma unroll
      for (int j = 0; j < 4; j++) {
        int rowc = wm * 32 + mi * 16 + q * 4 + j;
        int colc = wn * 64 + ni * 16 + r;
        *(unsigned short*)(sA2 + rowc * 512 + ((colc * 2) ^ (((q * 4 + j) & 7) << 4))) =
            f2bf(acc[mi][ni][j]);
      }
  __syncthreads();
  float* cs = stats + side * 512;
  if (tid < 256) {
    float2 a = red[tid * 2], c2 = red[tid * 2 + 1];
    atomicAdd(&cs[tid], a.x + c2.x);
    atomicAdd(&cs[256 + tid], a.y + c2.y);
  }
  for (int c = tid; c < 2048; c += 512) {   // 64 rows x 32 chunks of 16B
    int row = c >> 5, cb = (c & 31) * 16;
    float4 v = *(const float4*)(sA2 + row * 512 + (cb ^ ((row & 7) << 4)));
    *(float4*)(hout + (grow0 + row) * 256 + (c & 31) * 8) = v;
  }
}

// ---------------- per-graph sum of relu(bn(h)) ----------------
__global__ __launch_bounds__(256) void k_gsum(
    const unsigned short* __restrict__ h, const float* __restrict__ stats,
    const float* __restrict__ gamma, const float* __restrict__ beta,
    float* __restrict__ sg) {
  int b = blockIdx.x;            // 256 = 2 sides x 128 graphs
  int side = b >> 7, g = b & 127;
  int t = threadIdx.x;
  int c0 = (t & 63) * 4, rg = t >> 6;
  const float* cs = stats + side * 512;
  float sc[4], sh_[4];
#pragma unroll
  for (int j = 0; j < 4; j++) {
    float mu = cs[c0 + j] * (1.f / 32768.f);
    float var = cs[256 + c0 + j] * (1.f / 32768.f) - mu * mu;
    float s = gamma[c0 + j] * rsqrtf(var + 1e-5f);
    sc[j] = s; sh_[j] = beta[c0 + j] - mu * s;
  }
  size_t base = (size_t)side * NNODE + (size_t)g * 256;
  float acc = 0.f;
  for (int k = 0; k < 64; k++) {
    int row = rg + k * 4;
    ushort4 u = *(const ushort4*)(h + (base + row) * 256 + c0);
    acc += fmaxf(fmaf(bf2f(u.x), sc[0], sh_[0]), 0.f);
    acc += fmaxf(fmaf(bf2f(u.y), sc[1], sh_[1]), 0.f);
    acc += fmaxf(fmaf(bf2f(u.z), sc[2], sh_[2]), 0.f);
    acc += fmaxf(fmaf(bf2f(u.w), sc[3], sh_[3]), 0.f);
  }
  __shared__ float red[256];
  red[t] = acc;
  __syncthreads();
  if (t < 64) {
    float s = red[t] + red[t + 64] + red[t + 128] + red[t + 192];
#pragma unroll
    for (int m = 1; m < 64; m <<= 1) s += __shfl_xor(s, m, 64);
    if (t == 0) sg[b] = s;
  }
}

// ---------------- final: p = sg1 - sg2, min-max normalize, exp(-p) ----------------
__global__ void k_final(const float* __restrict__ sg1, const float* __restrict__ sg2,
                        float* __restrict__ out) {
  int t = threadIdx.x;   // 64 threads
  float a = sg1[t] - sg2[t];
  float b = sg1[t + 64] - sg2[t + 64];
  float mn = fminf(a, b), mx = fmaxf(a, b);
#pragma unroll
  for (int msk = 1; msk < 64; msk <<= 1) {
    mn = fminf(mn, __shfl_xor(mn, msk, 64));
    mx = fmaxf(mx, __shfl_xor(mx, msk, 64));
  }
  float inv = 1.0f / (mx - mn);
  out[t] = __expf(-(a - mn) * inv);
  out[t + 64] = __expf(-(b - mn) * inv);
}

// ---------------- host ----------------
extern "C" void kernel_launch(void* const* d_in, const int* in_sizes, int n_in,
                              void* d_out, int out_size, void* d_ws, size_t ws_size,
                              hipStream_t stream) {
  (void)in_sizes; (void)n_in; (void)out_size; (void)ws_size;
  const float* f1 = (const float*)d_in[0];
  const float* f2 = (const float*)d_in[1];
  const int* e1 = (const int*)d_in[2];
  const int* e2 = (const int*)d_in[3];
  const float* gw1 = (const float*)d_in[5];
  const float* gb1 = (const float*)d_in[6];
  const float* gw2 = (const float*)d_in[7];
  const float* gb2 = (const float*)d_in[8];
  const float* gga = (const float*)d_in[9];
  const float* gbe = (const float*)d_in[10];
  float* out = (float*)d_out;

  char* ws = (char*)d_ws;
  size_t o = 0;
  auto alloc = [&](size_t bytes) { void* p = ws + o; o += (bytes + 255) & ~(size_t)255; return p; };
  unsigned short* hbuf = (unsigned short*)alloc(2ull * NNODE * 256 * 2);
  unsigned short* aggr = (unsigned short*)alloc(2ull * NNODE * 256 * 2);
  unsigned short* Wt = (unsigned short*)alloc(6ull * 65536 * 2);
  float* stats = (float*)alloc(3 * 1024 * 4);      // [layer][side][{sum,sq}][256]
  float* sg = (float*)alloc(256 * 4);
  int* cnt = (int*)alloc(2 * NNODE * 4);
  int* off = (int*)alloc(2 * (NNODE + 64) * 4);
  int* cur = (int*)alloc(2 * NNODE * 4);
  int* srcs = (int*)alloc(2ull * NEDGE * 4);

  hipMemsetAsync(stats, 0, 3 * 1024 * 4, stream);
  hipMemsetAsync(cnt, 0, 2 * NNODE * 4, stream);

  k_conv<<<16384, 256, 0, stream>>>(f1, f2, hbuf);
  k_wprep<<<96, 256, 0, stream>>>(gw1, gw2, Wt);
  k_degree2<<<4096, 256, 0, stream>>>(e1, e2, cnt);
  k_scan2<<<2, 1024, 0, stream>>>(cnt, off, cur);
  k_scatter2<<<4096, 256, 0, stream>>>(e1, e2, cur, srcs);

  for (int l = 0; l < 3; l++) {
    if (l == 0)
      k_agg<false><<<8192, 256, 0, stream>>>(hbuf, off, srcs, nullptr, nullptr, nullptr, aggr);
    else
      k_agg<true><<<8192, 256, 0, stream>>>(hbuf, off, srcs, stats + (l - 1) * 1024,
                                            gga + (l - 1) * 256, gbe + (l - 1) * 256, aggr);
    k_gin<<<1024, 512, 0, stream>>>(aggr, Wt + (size_t)l * 65536, Wt + (size_t)(3 + l) * 65536,
                                    gb1 + l * 256, gb2 + l * 256, stats + l * 1024, hbuf);
  }

  k_gsum<<<256, 256, 0, stream>>>(hbuf, stats + 2 * 1024, gga + 512, gbe + 512, sg);
  k_final<<<1, 64, 0, stream>>>(sg, sg + 128, out);
}